// Round 10
// baseline (1416.337 us; speedup 1.0000x reference)
//
#include <hip/hip_runtime.h>

#define T_   256
#define F_   32
#define NBH  8      // batches per half; 2 halves/block -> 16/block, 256 blocks
#define TPB  1024   // 16 waves: waves 0-7 = half A, 8-15 = half B
#define IMW  104
#define PR1  260    // pre1 row stride (f32), 16B-aligned
#define PR2  132

typedef __attribute__((ext_vector_type(8))) short bf16x8;
typedef __attribute__((ext_vector_type(4))) float f32x4;

#define K1f  (-1.44269504f)   // -log2(e)   : sigmoid gates
#define K2f  (-2.88539008f)   // -2*log2(e) : tanh gate & tanh(c)

__device__ __forceinline__ unsigned short bf16_rne(float x){
    unsigned u = __float_as_uint(x);
    u += 0x7FFF + ((u >> 16) & 1);
    return (unsigned short)(u >> 16);
}
__device__ __forceinline__ void bf16_split(float x, unsigned short& h, unsigned short& l){
    h = bf16_rne(x);
    float xr = __uint_as_float(((unsigned)h) << 16);
    l = bf16_rne(x - xr);
}
__device__ __forceinline__ void make_frags_s(const float* __restrict__ p8, float s,
                                             bf16x8& fh, bf16x8& fl){
    #pragma unroll
    for (int e = 0; e < 8; ++e){
        unsigned short h, l; bf16_split(s * p8[e], h, l);
        fh[e] = (short)h; fl[e] = (short)l;
    }
}
__device__ __forceinline__ float sigm_pre(float p){   // p = -log2e*x
    return __builtin_amdgcn_rcpf(1.f + __builtin_amdgcn_exp2f(p));
}
__device__ __forceinline__ float tanh_pre(float p){   // p = -2log2e*x
    return fmaf(2.f, __builtin_amdgcn_rcpf(1.f + __builtin_amdgcn_exp2f(p)), -1.f);
}

#define MFMA(A,B,C) __builtin_amdgcn_mfma_f32_16x16x32_bf16((A),(B),(C),0,0,0)

// LDS-visibility barrier WITHOUT vmcnt drain (x-loads stay in flight).
__device__ __forceinline__ void step_barrier(){
    asm volatile("s_waitcnt lgkmcnt(0)" ::: "memory");
    __builtin_amdgcn_s_barrier();
}

// launch_bounds(1024): 16 waves = 4/EU -> 128-VGPR cap. Round-9 natural
// demand was exactly 128 with the same weight-fragment footprint.
__global__ __launch_bounds__(TPB) void lstm_mfma(
    const float* __restrict__ x,      // [4096,256,32]
    const float* __restrict__ W_ih1,  // [256,32]
    const float* __restrict__ W_hh1,  // [256,64]
    const float* __restrict__ b_ih1,  // [256]
    const float* __restrict__ b_hh1,  // [256]
    const float* __restrict__ W_ih2,  // [128,64]
    const float* __restrict__ W_hh2,  // [128,32]
    const float* __restrict__ b_ih2,  // [128]
    const float* __restrict__ b_hh2,  // [128]
    const float* __restrict__ W_fc1,  // [16,32]
    const float* __restrict__ b_fc1,  // [16]
    const float* __restrict__ W_fc2,  // [1,16]
    const float* __restrict__ b_fc2,  // [1]
    float* __restrict__ out)          // [4096]
{
    const int tid  = threadIdx.x;
    const int lane = tid & 63;
    const int wid  = tid >> 6;        // 0..15
    const int half = wid >> 3;        // 0 = A, 1 = B
    const int lwid = wid & 7;         // wave within half
    const int ltid = tid & 511;
    const int bb   = lane & 15;       // fragment col
    const int bbm  = bb & 7;          // col -> valid batch (8-15 duplicate 0-7)
    const int kg   = (lane >> 4) & 3; // k-group of 8
    const int b0   = blockIdx.x * (2 * NBH);
    const int bh0  = b0 + half * NBH;

    // per-half images (hi/lo bf16, double-buffered) + preact buffers
    __shared__ __align__(16) unsigned short i1h[2][2][NBH][IMW], i1l[2][2][NBH][IMW];
    __shared__ __align__(16) unsigned short i2h[2][2][NBH][IMW], i2l[2][2][NBH][IMW];
    __shared__ __align__(16) float pre1[2][NBH * PR1];
    __shared__ __align__(16) float pre2[2][NBH * PR2];
    __shared__ float hfin[2 * NBH][32];
    __shared__ float hd[2 * NBH][16];

    // ===== weight fragments (pre-scaled), round-9 tiling per half =====
    // lwid 0-3: L1, wave w owns rows 64g+16w (all 4 gates)
    // lwid 4-7: L2, j=lwid-4 owns gate j (rows 32j..32j+31, two 16-row tiles)
    bf16x8 wh[4][3], wl[4][3];
    f32x4  bfr[4];
    if (lwid < 4){
        #pragma unroll
        for (int g = 0; g < 4; ++g){
            const float s = (g == 2) ? K2f : K1f;
            const int r = 64*g + 16*lwid + bb;
            make_frags_s(&W_ih1[r*32 +      8*kg], s, wh[g][0], wl[g][0]);
            make_frags_s(&W_hh1[r*64 +      8*kg], s, wh[g][1], wl[g][1]);
            make_frags_s(&W_hh1[r*64 + 32 + 8*kg], s, wh[g][2], wl[g][2]);
            #pragma unroll
            for (int q = 0; q < 4; ++q){
                const int row = 64*g + 16*lwid + 4*kg + q;
                bfr[g][q] = s * (b_ih1[row] + b_hh1[row]);
            }
        }
    } else {
        const int j = lwid - 4;
        const float s = (j == 2) ? K2f : K1f;
        #pragma unroll
        for (int tt = 0; tt < 2; ++tt){
            const int r = 32*j + 16*tt + bb;
            make_frags_s(&W_ih2[r*64 +      8*kg], s, wh[tt][0], wl[tt][0]);
            make_frags_s(&W_ih2[r*64 + 32 + 8*kg], s, wh[tt][1], wl[tt][1]);
            make_frags_s(&W_hh2[r*32 +      8*kg], s, wh[tt][2], wl[tt][2]);
            #pragma unroll
            for (int q = 0; q < 4; ++q){
                const int row = 32*j + 16*tt + 4*kg + q;
                bfr[tt][q] = s * (b_ih2[row] + b_hh2[row]);
            }
        }
    }

    // ===== combine ownership: local wave owns batch lwid, lane = unit =====
    const int cw = lwid;
    const int cu = lane;              // L1 unit 0..63; L2 unit = cu (lanes<32)
    float c1 = 0.f, c2 = 0.f;

    // ===== x staging: ltid 256-511, one float each (8 batches x 32) =====
    const int xi = ltid - 256;
    const int xb = (xi >> 5) & 7;
    const int xf = xi & 31;
    const size_t xbase = (size_t)(bh0 + xb) * (T_*F_) + xf;
    float xc = 0.f;

    // ===== init: zero images, stage x(0), preload x(1) =====
    for (int i = tid; i < 2*2*NBH*IMW; i += TPB){
        (&i1h[0][0][0][0])[i] = 0; (&i1l[0][0][0][0])[i] = 0;
        (&i2h[0][0][0][0])[i] = 0; (&i2l[0][0][0][0])[i] = 0;
    }
    __syncthreads();
    if (ltid >= 256){
        unsigned short hh, hl;
        bf16_split(x[xbase], hh, hl);
        i1h[half][0][xb][xf] = hh; i1l[half][0][xb][xf] = hl;
        xc = x[xbase + F_];
    }
    __syncthreads();

    // ===== main loop: 515 single-phase iterations, anti-phased halves =====
    // half A: MFMA at even p (t=p/2), combine at odd p (t=p>>1)
    // half B: MFMA at odd  p (t=p>>1), combine at even p (t=(p>>1)-1)
    for (int p = 0; p <= 2*T_ + 2; ++p){
        if ((p & 1) == half){
            const int t = p >> 1;
            if (t <= T_){
                const int cur = t & 1;
                if (lwid < 4){
                    if (t < T_){
                        const unsigned short* ph = &i1h[half][cur][0][0] + bbm*IMW + 8*kg;
                        const unsigned short* pl = &i1l[half][cur][0][0] + bbm*IMW + 8*kg;
                        bf16x8 vh[3], vl[3];
                        #pragma unroll
                        for (int kb = 0; kb < 3; ++kb){
                            vh[kb] = *(const bf16x8*)(ph + 32*kb);
                            vl[kb] = *(const bf16x8*)(pl + 32*kb);
                        }
                        #pragma unroll
                        for (int g = 0; g < 4; ++g){
                            f32x4 a = bfr[g];
                            #pragma unroll
                            for (int kb = 0; kb < 3; ++kb) a = MFMA(wh[g][kb], vh[kb], a);
                            #pragma unroll
                            for (int kb = 0; kb < 3; ++kb) a = MFMA(wl[g][kb], vh[kb], a);
                            #pragma unroll
                            for (int kb = 0; kb < 3; ++kb) a = MFMA(wh[g][kb], vl[kb], a);
                            if (bb < NBH)
                                *(f32x4*)&pre1[half][bb*PR1 + 64*g + 16*lwid + 4*kg] = a;
                        }
                    }
                } else {
                    if (t > 0){
                        const int j = lwid - 4;
                        const unsigned short* ph = &i2h[half][cur][0][0] + bbm*IMW + 8*kg;
                        const unsigned short* pl = &i2l[half][cur][0][0] + bbm*IMW + 8*kg;
                        bf16x8 vh[3], vl[3];
                        #pragma unroll
                        for (int kb = 0; kb < 3; ++kb){
                            vh[kb] = *(const bf16x8*)(ph + 32*kb);
                            vl[kb] = *(const bf16x8*)(pl + 32*kb);
                        }
                        #pragma unroll
                        for (int tt = 0; tt < 2; ++tt){
                            f32x4 a = bfr[tt];
                            #pragma unroll
                            for (int kb = 0; kb < 3; ++kb) a = MFMA(wh[tt][kb], vh[kb], a);
                            #pragma unroll
                            for (int kb = 0; kb < 3; ++kb) a = MFMA(wl[tt][kb], vh[kb], a);
                            #pragma unroll
                            for (int kb = 0; kb < 3; ++kb) a = MFMA(wh[tt][kb], vl[kb], a);
                            if (bb < NBH)
                                *(f32x4*)&pre2[half][bb*PR2 + 32*j + 16*tt + 4*kg] = a;
                        }
                    }
                }
            }
        } else {
            const int t = (p >> 1) - half;
            if (t >= 0 && t <= T_){
                const int nxt = (t & 1) ^ 1;
                if (t < T_){
                    const float* pp = &pre1[half][cw*PR1];
                    const float i_ = sigm_pre(pp[cu]);
                    const float f_ = sigm_pre(pp[ 64 + cu]);
                    const float g_ = tanh_pre(pp[128 + cu]);
                    const float o_ = sigm_pre(pp[192 + cu]);
                    c1 = fmaf(f_, c1, i_ * g_);
                    const float h1 = o_ * tanh_pre(K2f * c1);
                    unsigned short hh, hl; bf16_split(h1, hh, hl);
                    i1h[half][nxt][cw][32 + cu] = hh; i1l[half][nxt][cw][32 + cu] = hl;
                    i2h[half][nxt][cw][cu]      = hh; i2l[half][nxt][cw][cu]      = hl;
                }
                if (t > 0 && cu < 32){
                    const float* pp = &pre2[half][cw*PR2];
                    const float i_ = sigm_pre(pp[cu]);
                    const float f_ = sigm_pre(pp[32 + cu]);
                    const float g_ = tanh_pre(pp[64 + cu]);
                    const float o_ = sigm_pre(pp[96 + cu]);
                    c2 = fmaf(f_, c2, i_ * g_);
                    const float h2 = o_ * tanh_pre(K2f * c2);
                    unsigned short hh, hl; bf16_split(h2, hh, hl);
                    i2h[half][nxt][cw][64 + cu] = hh; i2l[half][nxt][cw][64 + cu] = hl;
                    if (t == T_) hfin[half*NBH + cw][cu] = h2;
                }
                if (ltid >= 256 && t + 1 < T_){
                    unsigned short hh, hl; bf16_split(xc, hh, hl);
                    i1h[half][nxt][xb][xf] = hh; i1l[half][nxt][xb][xf] = hl;
                    const int tn = (t + 2 < T_) ? t + 2 : T_ - 1;
                    xc = x[xbase + (size_t)tn * F_];
                }
            }
        }
        step_barrier();
    }

    __syncthreads();
    // ===== head: fc1(16)+relu, fc2(1) over 16 batches =====
    if (tid < 2*NBH * 16){
        const int b = tid >> 4, j2 = tid & 15;
        float a = b_fc1[j2];
        #pragma unroll
        for (int k = 0; k < 32; ++k) a = fmaf(W_fc1[j2*32 + k], hfin[b][k], a);
        hd[b][j2] = fmaxf(a, 0.f);
    }
    __syncthreads();
    if (tid < 2*NBH){
        float a = b_fc2[0];
        #pragma unroll
        for (int k = 0; k < 16; ++k) a = fmaf(W_fc2[k], hd[tid][k], a);
        out[b0 + tid] = a;
    }
}

extern "C" void kernel_launch(void* const* d_in, const int* in_sizes, int n_in,
                              void* d_out, int out_size, void* d_ws, size_t ws_size,
                              hipStream_t stream) {
    const float* x     = (const float*)d_in[0];
    const float* W_ih1 = (const float*)d_in[1];
    const float* W_hh1 = (const float*)d_in[2];
    const float* b_ih1 = (const float*)d_in[3];
    const float* b_hh1 = (const float*)d_in[4];
    const float* W_ih2 = (const float*)d_in[5];
    const float* W_hh2 = (const float*)d_in[6];
    const float* b_ih2 = (const float*)d_in[7];
    const float* b_hh2 = (const float*)d_in[8];
    const float* W_fc1 = (const float*)d_in[9];
    const float* b_fc1 = (const float*)d_in[10];
    const float* W_fc2 = (const float*)d_in[11];
    const float* b_fc2 = (const float*)d_in[12];
    float* out = (float*)d_out;

    const int B = in_sizes[0] / (T_ * F_);   // 4096
    dim3 grid(B / (2 * NBH)), block(TPB);    // 256 blocks, 1/CU, 16 waves
    hipLaunchKernelGGL(lstm_mfma, grid, block, 0, stream,
                       x, W_ih1, W_hh1, b_ih1, b_hh1,
                       W_ih2, W_hh2, b_ih2, b_hh2,
                       W_fc1, b_fc1, W_fc2, b_fc2, out);
}

// Round 11
// 505.644 us; speedup vs baseline: 2.8011x; 2.8011x over previous
//
#include <hip/hip_runtime.h>

#define T_   256
#define F_   32
#define NBH  8      // batches per half; 16 per block; 256 blocks
#define TPB  512    // 8 waves: 0-3 pure-MFMA, 4-7 pure-combine
#define IMW  104
#define PR1  260    // pre1 row stride (f32), 16B-aligned
#define PR2  132

typedef __attribute__((ext_vector_type(8))) short bf16x8;
typedef __attribute__((ext_vector_type(4))) float f32x4;

#define K1f  (-1.44269504f)   // -log2(e)   : sigmoid gates
#define K2f  (-2.88539008f)   // -2*log2(e) : tanh gate & tanh(c)

__device__ __forceinline__ unsigned short bf16_rne(float x){
    unsigned u = __float_as_uint(x);
    u += 0x7FFF + ((u >> 16) & 1);
    return (unsigned short)(u >> 16);
}
__device__ __forceinline__ void bf16_split(float x, unsigned short& h, unsigned short& l){
    h = bf16_rne(x);
    float xr = __uint_as_float(((unsigned)h) << 16);
    l = bf16_rne(x - xr);
}
__device__ __forceinline__ void make_frags_s(const float* __restrict__ p8, float s,
                                             bf16x8& fh, bf16x8& fl){
    #pragma unroll
    for (int e = 0; e < 8; ++e){
        unsigned short h, l; bf16_split(s * p8[e], h, l);
        fh[e] = (short)h; fl[e] = (short)l;
    }
}
__device__ __forceinline__ float sigm_pre(float p){   // p = -log2e*x
    return __builtin_amdgcn_rcpf(1.f + __builtin_amdgcn_exp2f(p));
}
__device__ __forceinline__ float tanh_pre(float p){   // p = -2log2e*x
    return fmaf(2.f, __builtin_amdgcn_rcpf(1.f + __builtin_amdgcn_exp2f(p)), -1.f);
}

#define MFMA(A,B,C) __builtin_amdgcn_mfma_f32_16x16x32_bf16((A),(B),(C),0,0,0)

// LDS-visibility barrier WITHOUT vmcnt drain (x-loads stay in flight).
__device__ __forceinline__ void step_barrier(){
    asm volatile("s_waitcnt lgkmcnt(0)" ::: "memory");
    __builtin_amdgcn_s_barrier();
}

// (512,2): 256-VGPR cap. MFMA waves carry ~144 weight VGPRs + frags; DO NOT
// raise min-waves (rounds 2/7/10: any tighter cap spills and costs 3-6x).
__global__ __launch_bounds__(TPB, 2) void lstm_mfma(
    const float* __restrict__ x,      // [4096,256,32]
    const float* __restrict__ W_ih1,  // [256,32]
    const float* __restrict__ W_hh1,  // [256,64]
    const float* __restrict__ b_ih1,  // [256]
    const float* __restrict__ b_hh1,  // [256]
    const float* __restrict__ W_ih2,  // [128,64]
    const float* __restrict__ W_hh2,  // [128,32]
    const float* __restrict__ b_ih2,  // [128]
    const float* __restrict__ b_hh2,  // [128]
    const float* __restrict__ W_fc1,  // [16,32]
    const float* __restrict__ b_fc1,  // [16]
    const float* __restrict__ W_fc2,  // [1,16]
    const float* __restrict__ b_fc2,  // [1]
    float* __restrict__ out)          // [4096]
{
    const int tid  = threadIdx.x;
    const int lane = tid & 63;
    const int wid  = tid >> 6;        // 0..7
    const int bb   = lane & 15;       // fragment col
    const int bbm  = bb & 7;          // col -> batch within half (8-15 duplicate)
    const int kg   = (lane >> 4) & 3; // k-group of 8
    const int b0   = blockIdx.x * (2 * NBH);

    // per-half images (hi/lo bf16, double-buffered) + single-buffered preacts
    __shared__ __align__(16) unsigned short i1h[2][2][NBH][IMW], i1l[2][2][NBH][IMW];
    __shared__ __align__(16) unsigned short i2h[2][2][NBH][IMW], i2l[2][2][NBH][IMW];
    __shared__ __align__(16) float pre1[2][NBH * PR1];
    __shared__ __align__(16) float pre2[2][NBH * PR2];
    __shared__ float hfin[2 * NBH][32];
    __shared__ float hd[2 * NBH][16];

    // ===== MFMA waves (0-3): L1 rows 64g+16w (4 gate tiles) + L2 gate w (2 tiles) =====
    bf16x8 w1h[4][3], w1l[4][3], w2h[2][3], w2l[2][3];
    f32x4  b1f[4], b2f[2];
    if (wid < 4){
        #pragma unroll
        for (int g = 0; g < 4; ++g){
            const float s = (g == 2) ? K2f : K1f;
            const int r = 64*g + 16*wid + bb;
            make_frags_s(&W_ih1[r*32 +      8*kg], s, w1h[g][0], w1l[g][0]);
            make_frags_s(&W_hh1[r*64 +      8*kg], s, w1h[g][1], w1l[g][1]);
            make_frags_s(&W_hh1[r*64 + 32 + 8*kg], s, w1h[g][2], w1l[g][2]);
            #pragma unroll
            for (int q = 0; q < 4; ++q){
                const int row = 64*g + 16*wid + 4*kg + q;
                b1f[g][q] = s * (b_ih1[row] + b_hh1[row]);
            }
        }
        const float s2 = (wid == 2) ? K2f : K1f;   // L2 gate = wid
        #pragma unroll
        for (int tt = 0; tt < 2; ++tt){
            const int r = 32*wid + 16*tt + bb;
            make_frags_s(&W_ih2[r*64 +      8*kg], s2, w2h[tt][0], w2l[tt][0]);
            make_frags_s(&W_ih2[r*64 + 32 + 8*kg], s2, w2h[tt][1], w2l[tt][1]);
            make_frags_s(&W_hh2[r*32 +      8*kg], s2, w2h[tt][2], w2l[tt][2]);
            #pragma unroll
            for (int q = 0; q < 4; ++q){
                const int row = 32*wid + 16*tt + 4*kg + q;
                b2f[tt][q] = s2 * (b_ih2[row] + b_hh2[row]);
            }
        }
    }

    // ===== combine waves (4-7): thread (cb, uu) owns L1 units uu,uu+32; L2 unit uu =====
    const int ltid = tid - 256;           // 0..255 for combine waves
    const int cb   = (ltid >> 5) & 7;     // batch within half
    const int uu   = ltid & 31;
    float c1aA = 0.f, c1bA = 0.f, c2A = 0.f;   // half-0 cell state
    float c1aB = 0.f, c1bB = 0.f, c2B = 0.f;   // half-1 cell state

    // x staging: 1 float per combine thread per half (8b x 32f = 256)
    const size_t xbaseA = (size_t)(b0 + cb)       * (T_*F_) + uu;
    const size_t xbaseB = (size_t)(b0 + 8 + cb)   * (T_*F_) + uu;
    float xcA = 0.f, xcB = 0.f;

    // ===== init: zero images, stage x(0) both halves, preload x(1) =====
    for (int i = tid; i < 2*2*NBH*IMW; i += TPB){
        (&i1h[0][0][0][0])[i] = 0; (&i1l[0][0][0][0])[i] = 0;
        (&i2h[0][0][0][0])[i] = 0; (&i2l[0][0][0][0])[i] = 0;
    }
    __syncthreads();
    if (wid >= 4){
        unsigned short hh, hl;
        bf16_split(x[xbaseA], hh, hl);
        i1h[0][0][cb][uu] = hh; i1l[0][0][cb][uu] = hl;
        bf16_split(x[xbaseB], hh, hl);
        i1h[1][0][cb][uu] = hh; i1l[1][0][cb][uu] = hl;
        xcA = x[xbaseA + F_];
        xcB = x[xbaseB + F_];
    }
    __syncthreads();

    // ===== main loop: 515 phases. Phase p: MFMA waves -> half p&1 step p>>1;
    //       combine waves -> half 1-(p&1), step (p-1)>>1. One barrier/phase. =====
    for (int p = 0; p <= 2*T_ + 2; ++p){
        if (wid < 4){
            const int tm = p >> 1;
            const int hm = p & 1;
            if (tm <= T_){
                const int cur = tm & 1;
                if (tm < T_){   // L1 gates for step tm
                    const unsigned short* ph = &i1h[hm][cur][0][0] + bbm*IMW + 8*kg;
                    const unsigned short* pl = &i1l[hm][cur][0][0] + bbm*IMW + 8*kg;
                    bf16x8 vh[3], vl[3];
                    #pragma unroll
                    for (int kb = 0; kb < 3; ++kb){
                        vh[kb] = *(const bf16x8*)(ph + 32*kb);
                        vl[kb] = *(const bf16x8*)(pl + 32*kb);
                    }
                    #pragma unroll
                    for (int g = 0; g < 4; ++g){
                        f32x4 a = b1f[g];
                        #pragma unroll
                        for (int kb = 0; kb < 3; ++kb) a = MFMA(w1h[g][kb], vh[kb], a);
                        #pragma unroll
                        for (int kb = 0; kb < 3; ++kb) a = MFMA(w1l[g][kb], vh[kb], a);
                        #pragma unroll
                        for (int kb = 0; kb < 3; ++kb) a = MFMA(w1h[g][kb], vl[kb], a);
                        if (bb < NBH)
                            *(f32x4*)&pre1[hm][bb*PR1 + 64*g + 16*wid + 4*kg] = a;
                    }
                }
                if (tm > 0){    // L2 gates for h2(tm-1)
                    const unsigned short* ph = &i2h[hm][cur][0][0] + bbm*IMW + 8*kg;
                    const unsigned short* pl = &i2l[hm][cur][0][0] + bbm*IMW + 8*kg;
                    bf16x8 vh[3], vl[3];
                    #pragma unroll
                    for (int kb = 0; kb < 3; ++kb){
                        vh[kb] = *(const bf16x8*)(ph + 32*kb);
                        vl[kb] = *(const bf16x8*)(pl + 32*kb);
                    }
                    #pragma unroll
                    for (int tt = 0; tt < 2; ++tt){
                        f32x4 a = b2f[tt];
                        #pragma unroll
                        for (int kb = 0; kb < 3; ++kb) a = MFMA(w2h[tt][kb], vh[kb], a);
                        #pragma unroll
                        for (int kb = 0; kb < 3; ++kb) a = MFMA(w2l[tt][kb], vh[kb], a);
                        #pragma unroll
                        for (int kb = 0; kb < 3; ++kb) a = MFMA(w2h[tt][kb], vl[kb], a);
                        if (bb < NBH)
                            *(f32x4*)&pre2[hm][bb*PR2 + 32*wid + 16*tt + 4*kg] = a;
                    }
                }
            }
        } else if (p >= 1){
            const int tc = (p - 1) >> 1;
            const int hc = 1 - (p & 1);
            if (tc <= T_){
                const int nxt = (tc & 1) ^ 1;
                float& c1a = hc ? c1aB : c1aA;
                float& c1b = hc ? c1bB : c1bA;
                float& c2  = hc ? c2B  : c2A;
                float& xc  = hc ? xcB  : xcA;
                const size_t xbase = hc ? xbaseB : xbaseA;
                if (tc < T_){
                    const float* pp = &pre1[hc][cb*PR1];
                    {   // unit uu
                        const float i_ = sigm_pre(pp[uu]);
                        const float f_ = sigm_pre(pp[ 64 + uu]);
                        const float g_ = tanh_pre(pp[128 + uu]);
                        const float o_ = sigm_pre(pp[192 + uu]);
                        c1a = fmaf(f_, c1a, i_ * g_);
                        const float h1 = o_ * tanh_pre(K2f * c1a);
                        unsigned short hh, hl; bf16_split(h1, hh, hl);
                        i1h[hc][nxt][cb][32 + uu] = hh; i1l[hc][nxt][cb][32 + uu] = hl;
                        i2h[hc][nxt][cb][uu]      = hh; i2l[hc][nxt][cb][uu]      = hl;
                    }
                    {   // unit uu+32
                        const int u = uu + 32;
                        const float i_ = sigm_pre(pp[u]);
                        const float f_ = sigm_pre(pp[ 64 + u]);
                        const float g_ = tanh_pre(pp[128 + u]);
                        const float o_ = sigm_pre(pp[192 + u]);
                        c1b = fmaf(f_, c1b, i_ * g_);
                        const float h1 = o_ * tanh_pre(K2f * c1b);
                        unsigned short hh, hl; bf16_split(h1, hh, hl);
                        i1h[hc][nxt][cb][32 + u] = hh; i1l[hc][nxt][cb][32 + u] = hl;
                        i2h[hc][nxt][cb][u]      = hh; i2l[hc][nxt][cb][u]      = hl;
                    }
                }
                if (tc > 0){
                    const float* pp = &pre2[hc][cb*PR2];
                    const float i_ = sigm_pre(pp[uu]);
                    const float f_ = sigm_pre(pp[32 + uu]);
                    const float g_ = tanh_pre(pp[64 + uu]);
                    const float o_ = sigm_pre(pp[96 + uu]);
                    c2 = fmaf(f_, c2, i_ * g_);
                    const float h2 = o_ * tanh_pre(K2f * c2);
                    unsigned short hh, hl; bf16_split(h2, hh, hl);
                    i2h[hc][nxt][cb][64 + uu] = hh; i2l[hc][nxt][cb][64 + uu] = hl;
                    if (tc == T_) hfin[hc*NBH + cb][uu] = h2;
                }
                if (tc + 1 < T_){
                    // stage x(tc+1) (loaded 2 phases ago); issue load of x(tc+2)
                    unsigned short hh, hl; bf16_split(xc, hh, hl);
                    i1h[hc][nxt][cb][uu] = hh; i1l[hc][nxt][cb][uu] = hl;
                    const int tn = (tc + 2 < T_) ? tc + 2 : T_ - 1;
                    xc = x[xbase + (size_t)tn * F_];
                }
            }
        }
        step_barrier();
    }

    __syncthreads();
    // ===== head: fc1(16)+relu, fc2(1) over 16 batches =====
    if (tid < 2*NBH * 16){
        const int b = tid >> 4, j2 = tid & 15;
        float a = b_fc1[j2];
        #pragma unroll
        for (int k = 0; k < 32; ++k) a = fmaf(W_fc1[j2*32 + k], hfin[b][k], a);
        hd[b][j2] = fmaxf(a, 0.f);
    }
    __syncthreads();
    if (tid < 2*NBH){
        float a = b_fc2[0];
        #pragma unroll
        for (int k = 0; k < 16; ++k) a = fmaf(W_fc2[k], hd[tid][k], a);
        out[b0 + tid] = a;
    }
}

extern "C" void kernel_launch(void* const* d_in, const int* in_sizes, int n_in,
                              void* d_out, int out_size, void* d_ws, size_t ws_size,
                              hipStream_t stream) {
    const float* x     = (const float*)d_in[0];
    const float* W_ih1 = (const float*)d_in[1];
    const float* W_hh1 = (const float*)d_in[2];
    const float* b_ih1 = (const float*)d_in[3];
    const float* b_hh1 = (const float*)d_in[4];
    const float* W_ih2 = (const float*)d_in[5];
    const float* W_hh2 = (const float*)d_in[6];
    const float* b_ih2 = (const float*)d_in[7];
    const float* b_hh2 = (const float*)d_in[8];
    const float* W_fc1 = (const float*)d_in[9];
    const float* b_fc1 = (const float*)d_in[10];
    const float* W_fc2 = (const float*)d_in[11];
    const float* b_fc2 = (const float*)d_in[12];
    float* out = (float*)d_out;

    const int B = in_sizes[0] / (T_ * F_);   // 4096
    dim3 grid(B / (2 * NBH)), block(TPB);    // 256 blocks, 1/CU
    hipLaunchKernelGGL(lstm_mfma, grid, block, 0, stream,
                       x, W_ih1, W_hh1, b_ih1, b_hh1,
                       W_ih2, W_hh2, b_ih2, b_hh2,
                       W_fc1, b_fc1, W_fc2, b_fc2, out);
}

// Round 12
// 401.571 us; speedup vs baseline: 3.5270x; 1.2592x over previous
//
#include <hip/hip_runtime.h>

#define T_   256
#define F_   32
#define NBB  8      // batches per block -> 512 blocks = 2 blocks/CU co-resident
#define TPB  256    // 4 waves; each wave: L1 (4 gate tiles) + L2 (1 gate, 2 tiles)
#define IMW  104
#define PR1  260    // pre1 row stride (f32), 16B-aligned
#define PR2  132

typedef __attribute__((ext_vector_type(8))) short bf16x8;
typedef __attribute__((ext_vector_type(4))) float f32x4;

#define K1f  (-1.44269504f)   // -log2(e)   : sigmoid gates
#define K2f  (-2.88539008f)   // -2*log2(e) : tanh gate & tanh(c)

__device__ __forceinline__ unsigned short bf16_rne(float x){
    unsigned u = __float_as_uint(x);
    u += 0x7FFF + ((u >> 16) & 1);
    return (unsigned short)(u >> 16);
}
__device__ __forceinline__ void bf16_split(float x, unsigned short& h, unsigned short& l){
    h = bf16_rne(x);
    float xr = __uint_as_float(((unsigned)h) << 16);
    l = bf16_rne(x - xr);
}
__device__ __forceinline__ void make_frags_s(const float* __restrict__ p8, float s,
                                             bf16x8& fh, bf16x8& fl){
    #pragma unroll
    for (int e = 0; e < 8; ++e){
        unsigned short h, l; bf16_split(s * p8[e], h, l);
        fh[e] = (short)h; fl[e] = (short)l;
    }
}
__device__ __forceinline__ float sigm_pre(float p){   // p = -log2e*x
    return __builtin_amdgcn_rcpf(1.f + __builtin_amdgcn_exp2f(p));
}
__device__ __forceinline__ float tanh_pre(float p){   // p = -2log2e*x
    return fmaf(2.f, __builtin_amdgcn_rcpf(1.f + __builtin_amdgcn_exp2f(p)), -1.f);
}

#define MFMA(A,B,C) __builtin_amdgcn_mfma_f32_16x16x32_bf16((A),(B),(C),0,0,0)

// LDS-visibility barrier WITHOUT vmcnt drain (x-loads stay in flight).
__device__ __forceinline__ void step_barrier(){
    asm volatile("s_waitcnt lgkmcnt(0)" ::: "memory");
    __builtin_amdgcn_s_barrier();
}

// waves_per_eu(2,2): min=2 caps VGPR at 256; max=2 tells the allocator that
// occupancy beyond 2 waves/EU is pointless, so it must NOT shrink to 128 and
// spill (round-11 failure: heuristic chose 128 < the 256 cap and spilled).
__global__ __launch_bounds__(TPB) __attribute__((amdgpu_waves_per_eu(2, 2)))
void lstm_mfma(
    const float* __restrict__ x,      // [4096,256,32]
    const float* __restrict__ W_ih1,  // [256,32]
    const float* __restrict__ W_hh1,  // [256,64]
    const float* __restrict__ b_ih1,  // [256]
    const float* __restrict__ b_hh1,  // [256]
    const float* __restrict__ W_ih2,  // [128,64]
    const float* __restrict__ W_hh2,  // [128,32]
    const float* __restrict__ b_ih2,  // [128]
    const float* __restrict__ b_hh2,  // [128]
    const float* __restrict__ W_fc1,  // [16,32]
    const float* __restrict__ b_fc1,  // [16]
    const float* __restrict__ W_fc2,  // [1,16]
    const float* __restrict__ b_fc2,  // [1]
    float* __restrict__ out)          // [4096]
{
    const int tid  = threadIdx.x;
    const int lane = tid & 63;
    const int wid  = tid >> 6;        // 0..3
    const int bb   = lane & 15;       // fragment col
    const int bbm  = bb & 7;          // col -> batch (8-15 duplicate 0-7)
    const int kg   = (lane >> 4) & 3; // k-group of 8
    const int b0   = blockIdx.x * NBB;

    // img1 = [x(32)|h1(64)], img2 = [h1(64)|h2(32)]; hi/lo bf16, double-buffered
    __shared__ __align__(16) unsigned short i1h[2][NBB][IMW], i1l[2][NBB][IMW];
    __shared__ __align__(16) unsigned short i2h[2][NBB][IMW], i2l[2][NBB][IMW];
    __shared__ __align__(16) float pre1[NBB * PR1];
    __shared__ __align__(16) float pre2[NBB * PR2];
    __shared__ float hfin[NBB][32];
    __shared__ float hd[NBB][16];

    // ===== weight fragments (pre-scaled) =====
    // L1: wave w owns rows 64g+16w for g=0..3 (4 tiles).
    // L2: wave w owns gate w: rows 32w+16tt, tt=0,1 (2 tiles).
    bf16x8 w1h[4][3], w1l[4][3], w2h[2][3], w2l[2][3];
    f32x4  b1f[4], b2f[2];
    #pragma unroll
    for (int g = 0; g < 4; ++g){
        const float s = (g == 2) ? K2f : K1f;
        const int r = 64*g + 16*wid + bb;
        make_frags_s(&W_ih1[r*32 +      8*kg], s, w1h[g][0], w1l[g][0]);
        make_frags_s(&W_hh1[r*64 +      8*kg], s, w1h[g][1], w1l[g][1]);
        make_frags_s(&W_hh1[r*64 + 32 + 8*kg], s, w1h[g][2], w1l[g][2]);
        #pragma unroll
        for (int q = 0; q < 4; ++q){
            const int row = 64*g + 16*wid + 4*kg + q;
            b1f[g][q] = s * (b_ih1[row] + b_hh1[row]);
        }
    }
    {
        const float s2 = (wid == 2) ? K2f : K1f;   // L2 gate = wid
        #pragma unroll
        for (int tt = 0; tt < 2; ++tt){
            const int r = 32*wid + 16*tt + bb;
            make_frags_s(&W_ih2[r*64 +      8*kg], s2, w2h[tt][0], w2l[tt][0]);
            make_frags_s(&W_ih2[r*64 + 32 + 8*kg], s2, w2h[tt][1], w2l[tt][1]);
            make_frags_s(&W_hh2[r*32 +      8*kg], s2, w2h[tt][2], w2l[tt][2]);
            #pragma unroll
            for (int q = 0; q < 4; ++q){
                const int row = 32*wid + 16*tt + 4*kg + q;
                b2f[tt][q] = s2 * (b_ih2[row] + b_hh2[row]);
            }
        }
    }

    // ===== combine ownership: thread (cb, uu) owns L1 units uu,uu+32; L2 unit uu =====
    const int cb = tid >> 5;          // 0..7
    const int uu = tid & 31;
    float c1a = 0.f, c1b = 0.f, c2 = 0.f;

    // ===== x staging: every thread owns 1 float (8 batches x 32) =====
    const size_t xbase = (size_t)(b0 + cb) * (T_*F_) + uu;
    float xc = 0.f;

    // ===== init: zero images, stage x(0), preload x(1) =====
    for (int i = tid; i < 2*NBB*IMW; i += TPB){
        (&i1h[0][0][0])[i] = 0; (&i1l[0][0][0])[i] = 0;
        (&i2h[0][0][0])[i] = 0; (&i2l[0][0][0])[i] = 0;
    }
    __syncthreads();
    {
        unsigned short hh, hl;
        bf16_split(x[xbase], hh, hl);
        i1h[0][cb][uu] = hh; i1l[0][cb][uu] = hl;
        xc = x[xbase + F_];
    }
    __syncthreads();

    // ===== main loop: 2 phases/step; L2 lags L1 by one step =====
    for (int t = 0; t <= T_; ++t){
        const int cur = t & 1, nxt = cur ^ 1;

        // ---- phase 1: MFMA -> preact LDS (all 4 waves, both layers) ----
        if (t < T_){
            const unsigned short* ph = &i1h[cur][0][0] + bbm*IMW + 8*kg;
            const unsigned short* pl = &i1l[cur][0][0] + bbm*IMW + 8*kg;
            bf16x8 vh[3], vl[3];
            #pragma unroll
            for (int kb = 0; kb < 3; ++kb){
                vh[kb] = *(const bf16x8*)(ph + 32*kb);
                vl[kb] = *(const bf16x8*)(pl + 32*kb);
            }
            __builtin_amdgcn_s_setprio(1);
            f32x4 a0, a1, a2, a3;
            a0 = b1f[0]; a1 = b1f[1]; a2 = b1f[2]; a3 = b1f[3];
            #pragma unroll
            for (int kb = 0; kb < 3; ++kb){
                a0 = MFMA(w1h[0][kb], vh[kb], a0);
                a1 = MFMA(w1h[1][kb], vh[kb], a1);
                a2 = MFMA(w1h[2][kb], vh[kb], a2);
                a3 = MFMA(w1h[3][kb], vh[kb], a3);
            }
            #pragma unroll
            for (int kb = 0; kb < 3; ++kb){
                a0 = MFMA(w1l[0][kb], vh[kb], a0);
                a1 = MFMA(w1l[1][kb], vh[kb], a1);
                a2 = MFMA(w1l[2][kb], vh[kb], a2);
                a3 = MFMA(w1l[3][kb], vh[kb], a3);
            }
            #pragma unroll
            for (int kb = 0; kb < 3; ++kb){
                a0 = MFMA(w1h[0][kb], vl[kb], a0);
                a1 = MFMA(w1h[1][kb], vl[kb], a1);
                a2 = MFMA(w1h[2][kb], vl[kb], a2);
                a3 = MFMA(w1h[3][kb], vl[kb], a3);
            }
            __builtin_amdgcn_s_setprio(0);
            if (bb < NBB){
                *(f32x4*)&pre1[bb*PR1 +       16*wid + 4*kg] = a0;
                *(f32x4*)&pre1[bb*PR1 +  64 + 16*wid + 4*kg] = a1;
                *(f32x4*)&pre1[bb*PR1 + 128 + 16*wid + 4*kg] = a2;
                *(f32x4*)&pre1[bb*PR1 + 192 + 16*wid + 4*kg] = a3;
            }
        }
        if (t > 0){
            const unsigned short* ph = &i2h[cur][0][0] + bbm*IMW + 8*kg;
            const unsigned short* pl = &i2l[cur][0][0] + bbm*IMW + 8*kg;
            bf16x8 vh[3], vl[3];
            #pragma unroll
            for (int kb = 0; kb < 3; ++kb){
                vh[kb] = *(const bf16x8*)(ph + 32*kb);
                vl[kb] = *(const bf16x8*)(pl + 32*kb);
            }
            __builtin_amdgcn_s_setprio(1);
            f32x4 a0 = b2f[0], a1 = b2f[1];
            #pragma unroll
            for (int kb = 0; kb < 3; ++kb){
                a0 = MFMA(w2h[0][kb], vh[kb], a0);
                a1 = MFMA(w2h[1][kb], vh[kb], a1);
            }
            #pragma unroll
            for (int kb = 0; kb < 3; ++kb){
                a0 = MFMA(w2l[0][kb], vh[kb], a0);
                a1 = MFMA(w2l[1][kb], vh[kb], a1);
            }
            #pragma unroll
            for (int kb = 0; kb < 3; ++kb){
                a0 = MFMA(w2h[0][kb], vl[kb], a0);
                a1 = MFMA(w2h[1][kb], vl[kb], a1);
            }
            __builtin_amdgcn_s_setprio(0);
            if (bb < NBB){
                *(f32x4*)&pre2[bb*PR2 + 32*wid +      4*kg] = a0;
                *(f32x4*)&pre2[bb*PR2 + 32*wid + 16 + 4*kg] = a1;
            }
        }
        step_barrier();   // pre1/pre2 visible; img[cur] reads done

        // ---- phase 2: combine (3 units/thread) + img[nxt] writes ----
        if (t < T_){
            const float* p = &pre1[cb*PR1];
            {
                const float i_ = sigm_pre(p[uu]);
                const float f_ = sigm_pre(p[ 64 + uu]);
                const float g_ = tanh_pre(p[128 + uu]);
                const float o_ = sigm_pre(p[192 + uu]);
                c1a = fmaf(f_, c1a, i_ * g_);
                const float h1 = o_ * tanh_pre(K2f * c1a);
                unsigned short hh, hl; bf16_split(h1, hh, hl);
                i1h[nxt][cb][32 + uu] = hh; i1l[nxt][cb][32 + uu] = hl;
                i2h[nxt][cb][uu]      = hh; i2l[nxt][cb][uu]      = hl;
            }
            {
                const int u = uu + 32;
                const float i_ = sigm_pre(p[u]);
                const float f_ = sigm_pre(p[ 64 + u]);
                const float g_ = tanh_pre(p[128 + u]);
                const float o_ = sigm_pre(p[192 + u]);
                c1b = fmaf(f_, c1b, i_ * g_);
                const float h1 = o_ * tanh_pre(K2f * c1b);
                unsigned short hh, hl; bf16_split(h1, hh, hl);
                i1h[nxt][cb][32 + u] = hh; i1l[nxt][cb][32 + u] = hl;
                i2h[nxt][cb][u]      = hh; i2l[nxt][cb][u]      = hl;
            }
        }
        if (t > 0){
            const float* p = &pre2[cb*PR2];
            const float i_ = sigm_pre(p[uu]);
            const float f_ = sigm_pre(p[32 + uu]);
            const float g_ = tanh_pre(p[64 + uu]);
            const float o_ = sigm_pre(p[96 + uu]);
            c2 = fmaf(f_, c2, i_ * g_);
            const float h2 = o_ * tanh_pre(K2f * c2);
            unsigned short hh, hl; bf16_split(h2, hh, hl);
            i2h[nxt][cb][64 + uu] = hh; i2l[nxt][cb][64 + uu] = hl;
            if (t == T_) hfin[cb][uu] = h2;
        }
        if (t + 1 < T_){
            // stage x(t+1) (loaded a full step ago); issue load of x(t+2)
            unsigned short hh, hl; bf16_split(xc, hh, hl);
            i1h[nxt][cb][uu] = hh; i1l[nxt][cb][uu] = hl;
            const int tn = (t + 2 < T_) ? t + 2 : T_ - 1;
            xc = x[xbase + (size_t)tn * F_];
        }
        step_barrier();
    }

    __syncthreads();
    // ===== head: fc1(16)+relu, fc2(1) =====
    if (tid < NBB * 16){
        const int b = tid >> 4, j2 = tid & 15;
        float a = b_fc1[j2];
        #pragma unroll
        for (int k = 0; k < 32; ++k) a = fmaf(W_fc1[j2*32 + k], hfin[b][k], a);
        hd[b][j2] = fmaxf(a, 0.f);
    }
    __syncthreads();
    if (tid < NBB){
        float a = b_fc2[0];
        #pragma unroll
        for (int k = 0; k < 16; ++k) a = fmaf(W_fc2[k], hd[tid][k], a);
        out[b0 + tid] = a;
    }
}

extern "C" void kernel_launch(void* const* d_in, const int* in_sizes, int n_in,
                              void* d_out, int out_size, void* d_ws, size_t ws_size,
                              hipStream_t stream) {
    const float* x     = (const float*)d_in[0];
    const float* W_ih1 = (const float*)d_in[1];
    const float* W_hh1 = (const float*)d_in[2];
    const float* b_ih1 = (const float*)d_in[3];
    const float* b_hh1 = (const float*)d_in[4];
    const float* W_ih2 = (const float*)d_in[5];
    const float* W_hh2 = (const float*)d_in[6];
    const float* b_ih2 = (const float*)d_in[7];
    const float* b_hh2 = (const float*)d_in[8];
    const float* W_fc1 = (const float*)d_in[9];
    const float* b_fc1 = (const float*)d_in[10];
    const float* W_fc2 = (const float*)d_in[11];
    const float* b_fc2 = (const float*)d_in[12];
    float* out = (float*)d_out;

    const int B = in_sizes[0] / (T_ * F_);   // 4096
    dim3 grid(B / NBB), block(TPB);          // 512 blocks = 2 per CU
    hipLaunchKernelGGL(lstm_mfma, grid, block, 0, stream,
                       x, W_ih1, W_hh1, b_ih1, b_hh1,
                       W_ih2, W_hh2, b_ih2, b_hh2,
                       W_fc1, b_fc1, W_fc2, b_fc2, out);
}

// Round 13
// 287.861 us; speedup vs baseline: 4.9202x; 1.3950x over previous
//
#include <hip/hip_runtime.h>

#define T_   256
#define F_   32
#define NBB  16     // full 16-wide fragments: NEVER shrink below 16 (r12 lesson)
#define TPB  512    // 8 waves: 0-3 L1-role, 4-7 L2-role
#define IMW  104
#define PR1  260    // pre1 row stride (f32), 16B-aligned
#define PR2  132

typedef __attribute__((ext_vector_type(8))) short bf16x8;
typedef __attribute__((ext_vector_type(4))) float f32x4;
typedef __attribute__((ext_vector_type(4))) unsigned short ush4;

#define K1f  (-1.44269504f)   // -log2(e)   : sigmoid gates
#define K2f  (-2.88539008f)   // -2*log2(e) : tanh gate & tanh(c)

__device__ __forceinline__ unsigned short bf16_rne(float x){
    unsigned u = __float_as_uint(x);
    u += 0x7FFF + ((u >> 16) & 1);
    return (unsigned short)(u >> 16);
}
__device__ __forceinline__ void bf16_split(float x, unsigned short& h, unsigned short& l){
    h = bf16_rne(x);
    float xr = __uint_as_float(((unsigned)h) << 16);
    l = bf16_rne(x - xr);
}
__device__ __forceinline__ void make_frags_s(const float* __restrict__ p8, float s,
                                             bf16x8& fh, bf16x8& fl){
    #pragma unroll
    for (int e = 0; e < 8; ++e){
        unsigned short h, l; bf16_split(s * p8[e], h, l);
        fh[e] = (short)h; fl[e] = (short)l;
    }
}
__device__ __forceinline__ float sigm_pre(float p){   // p = -log2e*x
    return __builtin_amdgcn_rcpf(1.f + __builtin_amdgcn_exp2f(p));
}
__device__ __forceinline__ float tanh_pre(float p){   // p = -2log2e*x
    return fmaf(2.f, __builtin_amdgcn_rcpf(1.f + __builtin_amdgcn_exp2f(p)), -1.f);
}

#define MFMA(A,B,C) __builtin_amdgcn_mfma_f32_16x16x32_bf16((A),(B),(C),0,0,0)

// LDS-visibility barrier WITHOUT vmcnt drain (x-loads stay in flight).
__device__ __forceinline__ void step_barrier(){
    asm volatile("s_waitcnt lgkmcnt(0)" ::: "memory");
    __builtin_amdgcn_s_barrier();
}

// (512,2): the proven register envelope (r6/r8/r9: ~124-128 VGPR, no/benign spill).
__global__ __launch_bounds__(TPB, 2) void lstm_mfma(
    const float* __restrict__ x,      // [4096,256,32]
    const float* __restrict__ W_ih1,  // [256,32]
    const float* __restrict__ W_hh1,  // [256,64]
    const float* __restrict__ b_ih1,  // [256]
    const float* __restrict__ b_hh1,  // [256]
    const float* __restrict__ W_ih2,  // [128,64]
    const float* __restrict__ W_hh2,  // [128,32]
    const float* __restrict__ b_ih2,  // [128]
    const float* __restrict__ b_hh2,  // [128]
    const float* __restrict__ W_fc1,  // [16,32]
    const float* __restrict__ b_fc1,  // [16]
    const float* __restrict__ W_fc2,  // [1,16]
    const float* __restrict__ b_fc2,  // [1]
    float* __restrict__ out)          // [4096]
{
    const int tid  = threadIdx.x;
    const int lane = tid & 63;
    const int wid  = tid >> 6;        // 0..7
    const int bb   = lane & 15;       // fragment col = batch (all 16 real)
    const int kg   = (lane >> 4) & 3; // k-group of 8
    const int b0   = blockIdx.x * NBB;

    // i1 = [x(32)|h1(64)] x2 buffers; i2 = [h1(64)|h2(32)] x2 buffers (parity-indexed)
    __shared__ __align__(16) unsigned short i1h[2][NBB][IMW], i1l[2][NBB][IMW];
    __shared__ __align__(16) unsigned short i2h[2][NBB][IMW], i2l[2][NBB][IMW];
    __shared__ __align__(16) float pre1[NBB * PR1];
    __shared__ __align__(16) float pre2[NBB * PR2];
    __shared__ float hfin[NBB][32];
    __shared__ float hd[NBB][16];

    // ===== weight fragments (pre-scaled) =====
    // L1 waves (0-3): wave w owns rows 64g+16w for g=0..3.
    // L2 waves (4-7): j=wid-4 owns gate j (rows 32j+16tt, tt=0,1).
    bf16x8 wh[4][3], wl[4][3];
    f32x4  bfr[4];
    if (wid < 4){
        #pragma unroll
        for (int g = 0; g < 4; ++g){
            const float s = (g == 2) ? K2f : K1f;
            const int r = 64*g + 16*wid + bb;
            make_frags_s(&W_ih1[r*32 +      8*kg], s, wh[g][0], wl[g][0]);
            make_frags_s(&W_hh1[r*64 +      8*kg], s, wh[g][1], wl[g][1]);
            make_frags_s(&W_hh1[r*64 + 32 + 8*kg], s, wh[g][2], wl[g][2]);
            #pragma unroll
            for (int q = 0; q < 4; ++q){
                const int row = 64*g + 16*wid + 4*kg + q;
                bfr[g][q] = s * (b_ih1[row] + b_hh1[row]);
            }
        }
    } else {
        const int j = wid - 4;
        const float s = (j == 2) ? K2f : K1f;
        #pragma unroll
        for (int tt = 0; tt < 2; ++tt){
            const int r = 32*j + 16*tt + bb;
            make_frags_s(&W_ih2[r*64 +      8*kg], s, wh[tt][0], wl[tt][0]);
            make_frags_s(&W_ih2[r*64 + 32 + 8*kg], s, wh[tt][1], wl[tt][1]);
            make_frags_s(&W_hh2[r*32 +      8*kg], s, wh[tt][2], wl[tt][2]);
            #pragma unroll
            for (int q = 0; q < 4; ++q){
                const int row = 32*j + 16*tt + 4*kg + q;
                bfr[tt][q] = s * (b_ih2[row] + b_hh2[row]);
            }
        }
    }

    // ===== combine ownership =====
    // L1 threads (tid<256): batch cb1 = tid>>4, units u0..u0+3, u0=(tid&15)*4
    const int cb1 = tid >> 4;
    const int u0  = (tid & 15) * 4;
    float c10 = 0.f, c11 = 0.f, c12 = 0.f, c13 = 0.f;
    // L2 threads (tid>=256): lt = tid-256, batch cb2 = lt>>4, units v0, v0+1
    const int lt  = tid & 255;
    const int cb2 = lt >> 4;
    const int v0  = (lt & 15) * 2;
    float c20 = 0.f, c21 = 0.f;

    // x-staging on L1 threads: 2 consecutive floats (xf even)
    const int xf = (tid & 15) * 2;
    const size_t xbase = (size_t)(b0 + cb1) * (T_*F_) + xf;
    float2 xc = make_float2(0.f, 0.f);

    // ===== init: zero images, stage x(0), preload x(1) =====
    for (int i = tid; i < 2*NBB*IMW; i += TPB){
        (&i1h[0][0][0])[i] = 0; (&i1l[0][0][0])[i] = 0;
        (&i2h[0][0][0])[i] = 0; (&i2l[0][0][0])[i] = 0;
    }
    __syncthreads();
    if (wid < 4){
        float2 x0 = *(const float2*)&x[xbase];
        unsigned short hh, hl;
        bf16_split(x0.x, hh, hl); i1h[0][cb1][xf]   = hh; i1l[0][cb1][xf]   = hl;
        bf16_split(x0.y, hh, hl); i1h[0][cb1][xf+1] = hh; i1l[0][cb1][xf+1] = hl;
        xc = *(const float2*)&x[xbase + F_];
    }
    __syncthreads();

    // ===== main loop: anti-phased roles =====
    // P1: L1-MFMA(t)        ||  L2-combine(t-2)
    // P2: L1-combine(t)+x   ||  L2-MFMA(t-1)
    for (int t = 0; t <= T_ + 1; ++t){
        // ---------- P1 ----------
        if (wid < 4){
            if (t < T_){
                const int cur = t & 1;
                const unsigned short* ph = &i1h[cur][0][0] + bb*IMW + 8*kg;
                const unsigned short* pl = &i1l[cur][0][0] + bb*IMW + 8*kg;
                bf16x8 vh[3], vl[3];
                #pragma unroll
                for (int kb = 0; kb < 3; ++kb){
                    vh[kb] = *(const bf16x8*)(ph + 32*kb);
                    vl[kb] = *(const bf16x8*)(pl + 32*kb);
                }
                __builtin_amdgcn_s_setprio(1);
                f32x4 a0 = bfr[0], a1 = bfr[1], a2 = bfr[2], a3 = bfr[3];
                #pragma unroll
                for (int kb = 0; kb < 3; ++kb){
                    a0 = MFMA(wh[0][kb], vh[kb], a0);
                    a1 = MFMA(wh[1][kb], vh[kb], a1);
                    a2 = MFMA(wh[2][kb], vh[kb], a2);
                    a3 = MFMA(wh[3][kb], vh[kb], a3);
                }
                #pragma unroll
                for (int kb = 0; kb < 3; ++kb){
                    a0 = MFMA(wl[0][kb], vh[kb], a0);
                    a1 = MFMA(wl[1][kb], vh[kb], a1);
                    a2 = MFMA(wl[2][kb], vh[kb], a2);
                    a3 = MFMA(wl[3][kb], vh[kb], a3);
                }
                #pragma unroll
                for (int kb = 0; kb < 3; ++kb){
                    a0 = MFMA(wh[0][kb], vl[kb], a0);
                    a1 = MFMA(wh[1][kb], vl[kb], a1);
                    a2 = MFMA(wh[2][kb], vl[kb], a2);
                    a3 = MFMA(wh[3][kb], vl[kb], a3);
                }
                __builtin_amdgcn_s_setprio(0);
                *(f32x4*)&pre1[bb*PR1 +       16*wid + 4*kg] = a0;
                *(f32x4*)&pre1[bb*PR1 +  64 + 16*wid + 4*kg] = a1;
                *(f32x4*)&pre1[bb*PR1 + 128 + 16*wid + 4*kg] = a2;
                *(f32x4*)&pre1[bb*PR1 + 192 + 16*wid + 4*kg] = a3;
            }
        } else {
            const int m = t - 2;   // L2-combine step
            if (m >= 0 && m < T_){
                const float* p = &pre2[cb2*PR2];
                const float2 gi = *(const float2*)&p[     v0];
                const float2 gf = *(const float2*)&p[32 + v0];
                const float2 gg = *(const float2*)&p[64 + v0];
                const float2 go = *(const float2*)&p[96 + v0];
                const float i0 = sigm_pre(gi.x), i1_ = sigm_pre(gi.y);
                const float f0 = sigm_pre(gf.x), f1 = sigm_pre(gf.y);
                const float g0 = tanh_pre(gg.x), g1 = tanh_pre(gg.y);
                const float o0 = sigm_pre(go.x), o1 = sigm_pre(go.y);
                c20 = fmaf(f0, c20, i0 * g0);
                c21 = fmaf(f1, c21, i1_ * g1);
                const float h0 = o0 * tanh_pre(K2f * c20);
                const float h1 = o1 * tanh_pre(K2f * c21);
                unsigned short h0h, h0l, h1h, h1l;
                bf16_split(h0, h0h, h0l); bf16_split(h1, h1h, h1l);
                const int buf = (t - 1) & 1;   // consumed by L2-MFMA(t-1) in P2
                *(unsigned*)&i2h[buf][cb2][64 + v0] = (unsigned)h0h | ((unsigned)h1h << 16);
                *(unsigned*)&i2l[buf][cb2][64 + v0] = (unsigned)h0l | ((unsigned)h1l << 16);
                if (m == T_ - 1){ hfin[cb2][v0] = h0; hfin[cb2][v0+1] = h1; }
            }
        }
        step_barrier();

        // ---------- P2 ----------
        if (wid < 4){
            if (t < T_){
                const int nxt = (t & 1) ^ 1;
                const float* p = &pre1[cb1*PR1];
                const f32x4 gi = *(const f32x4*)&p[      u0];
                const f32x4 gf = *(const f32x4*)&p[ 64 + u0];
                const f32x4 gg = *(const f32x4*)&p[128 + u0];
                const f32x4 go = *(const f32x4*)&p[192 + u0];
                ush4 HH, HL;
                #pragma unroll
                for (int q = 0; q < 4; ++q){
                    const float i_ = sigm_pre(gi[q]);
                    const float f_ = sigm_pre(gf[q]);
                    const float g_ = tanh_pre(gg[q]);
                    const float o_ = sigm_pre(go[q]);
                    float c = (q==0)?c10:(q==1)?c11:(q==2)?c12:c13;
                    c = fmaf(f_, c, i_ * g_);
                    if (q==0) c10=c; else if (q==1) c11=c; else if (q==2) c12=c; else c13=c;
                    const float h = o_ * tanh_pre(K2f * c);
                    unsigned short hh, hl; bf16_split(h, hh, hl);
                    HH[q] = hh; HL[q] = hl;
                }
                *(ush4*)&i1h[nxt][cb1][32 + u0] = HH;
                *(ush4*)&i1l[nxt][cb1][32 + u0] = HL;
                *(ush4*)&i2h[t & 1][cb1][u0]    = HH;   // h1(t) -> i2[t&1]
                *(ush4*)&i2l[t & 1][cb1][u0]    = HL;
                if (t + 1 < T_){
                    unsigned short hh, hl;
                    bf16_split(xc.x, hh, hl);
                    unsigned w0 = hh, w0l = hl;
                    bf16_split(xc.y, hh, hl);
                    *(unsigned*)&i1h[nxt][cb1][xf] = w0  | ((unsigned)hh << 16);
                    *(unsigned*)&i1l[nxt][cb1][xf] = w0l | ((unsigned)hl << 16);
                    const int tn = (t + 2 < T_) ? t + 2 : T_ - 1;
                    xc = *(const float2*)&x[xbase + (size_t)tn * F_];
                }
            }
        } else {
            const int k = t - 1;   // L2-MFMA step
            if (k >= 0 && k < T_){
                const int buf = k & 1;
                const unsigned short* ph = &i2h[buf][0][0] + bb*IMW + 8*kg;
                const unsigned short* pl = &i2l[buf][0][0] + bb*IMW + 8*kg;
                bf16x8 vh[3], vl[3];
                #pragma unroll
                for (int kb = 0; kb < 3; ++kb){
                    vh[kb] = *(const bf16x8*)(ph + 32*kb);
                    vl[kb] = *(const bf16x8*)(pl + 32*kb);
                }
                __builtin_amdgcn_s_setprio(1);
                f32x4 a0 = bfr[0], a1 = bfr[1];
                #pragma unroll
                for (int kb = 0; kb < 3; ++kb){
                    a0 = MFMA(wh[0][kb], vh[kb], a0);
                    a1 = MFMA(wh[1][kb], vh[kb], a1);
                }
                #pragma unroll
                for (int kb = 0; kb < 3; ++kb){
                    a0 = MFMA(wl[0][kb], vh[kb], a0);
                    a1 = MFMA(wl[1][kb], vh[kb], a1);
                }
                #pragma unroll
                for (int kb = 0; kb < 3; ++kb){
                    a0 = MFMA(wh[0][kb], vl[kb], a0);
                    a1 = MFMA(wh[1][kb], vl[kb], a1);
                }
                __builtin_amdgcn_s_setprio(0);
                const int j = wid - 4;
                *(f32x4*)&pre2[bb*PR2 + 32*j +      4*kg] = a0;
                *(f32x4*)&pre2[bb*PR2 + 32*j + 16 + 4*kg] = a1;
            }
        }
        step_barrier();
    }

    __syncthreads();
    // ===== head: fc1(16)+relu, fc2(1) =====
    if (tid < NBB * 16){
        const int b = tid >> 4, j2 = tid & 15;
        float a = b_fc1[j2];
        #pragma unroll
        for (int k = 0; k < 32; ++k) a = fmaf(W_fc1[j2*32 + k], hfin[b][k], a);
        hd[b][j2] = fmaxf(a, 0.f);
    }
    __syncthreads();
    if (tid < NBB){
        float a = b_fc2[0];
        #pragma unroll
        for (int k = 0; k < 16; ++k) a = fmaf(W_fc2[k], hd[tid][k], a);
        out[b0 + tid] = a;
    }
}

extern "C" void kernel_launch(void* const* d_in, const int* in_sizes, int n_in,
                              void* d_out, int out_size, void* d_ws, size_t ws_size,
                              hipStream_t stream) {
    const float* x     = (const float*)d_in[0];
    const float* W_ih1 = (const float*)d_in[1];
    const float* W_hh1 = (const float*)d_in[2];
    const float* b_ih1 = (const float*)d_in[3];
    const float* b_hh1 = (const float*)d_in[4];
    const float* W_ih2 = (const float*)d_in[5];
    const float* W_hh2 = (const float*)d_in[6];
    const float* b_ih2 = (const float*)d_in[7];
    const float* b_hh2 = (const float*)d_in[8];
    const float* W_fc1 = (const float*)d_in[9];
    const float* b_fc1 = (const float*)d_in[10];
    const float* W_fc2 = (const float*)d_in[11];
    const float* b_fc2 = (const float*)d_in[12];
    float* out = (float*)d_out;

    const int B = in_sizes[0] / (T_ * F_);   // 4096
    dim3 grid(B / NBB), block(TPB);          // 256 blocks, 1/CU
    hipLaunchKernelGGL(lstm_mfma, grid, block, 0, stream,
                       x, W_ih1, W_hh1, b_ih1, b_hh1,
                       W_ih2, W_hh2, b_ih2, b_hh2,
                       W_fc1, b_fc1, W_fc2, b_fc2, out);
}